// Round 2
// baseline (85.892 us; speedup 1.0000x reference)
//
#include <hip/hip_runtime.h>
#include <math.h>

#define NGAUSS 2000
#define IMW 128
#define IMH 128
#define NPIX (IMW*IMH)
#define PSTRIDE 12
#define CHUNK 250

// ---------------- preprocess: per-gaussian params ----------------
__global__ __launch_bounds__(256) void prep_kernel(
    const float* __restrict__ means3D, const float* __restrict__ covs3d,
    const float* __restrict__ colors, const float* __restrict__ opac,
    const float* __restrict__ Km, const float* __restrict__ Rm,
    const float* __restrict__ tv,
    float* __restrict__ params, float* __restrict__ depths)
{
    int i = blockIdx.x * 256 + threadIdx.x;
    if (i >= NGAUSS) return;

    float R0 = Rm[0], R1 = Rm[1], R2 = Rm[2];
    float R3 = Rm[3], R4 = Rm[4], R5 = Rm[5];
    float R6 = Rm[6], R7 = Rm[7], R8 = Rm[8];

    float mx = means3D[3*i+0], my = means3D[3*i+1], mz = means3D[3*i+2];
    float camx = R0*mx + R1*my + R2*mz + tv[0];
    float camy = R3*mx + R4*my + R5*mz + tv[1];
    float camz = R6*mx + R7*my + R8*mz + tv[2];

    float depth = fmaxf(camz, 1.0f);
    bool valid = (depth > 1.0f) && (depth < 50.0f);

    float fx = Km[0], cx = Km[2], fy = Km[4], cy = Km[5];
    float invz = 1.0f / camz;
    float m2x = (fx*camx + cx*camz) * invz;
    float m2y = (fy*camy + cy*camz) * invz;

    // Jacobian rows: J0 = (J00, 0, J02), J1 = (0, J11, J12); tz = camz (unclamped, per reference)
    float J00 = fx*invz, J02 = -fx*camx*invz*invz;
    float J11 = fy*invz, J12 = -fy*camy*invz*invz;

    float S0 = covs3d[9*i+0], S1 = covs3d[9*i+1], S2 = covs3d[9*i+2];
    float S3 = covs3d[9*i+3], S4 = covs3d[9*i+4], S5 = covs3d[9*i+5];
    float S6 = covs3d[9*i+6], S7 = covs3d[9*i+7], S8 = covs3d[9*i+8];

    // RS = R * S
    float RS0 = R0*S0 + R1*S3 + R2*S6;
    float RS1 = R0*S1 + R1*S4 + R2*S7;
    float RS2 = R0*S2 + R1*S5 + R2*S8;
    float RS3 = R3*S0 + R4*S3 + R5*S6;
    float RS4 = R3*S1 + R4*S4 + R5*S7;
    float RS5 = R3*S2 + R4*S5 + R5*S8;
    float RS6 = R6*S0 + R7*S3 + R8*S6;
    float RS7 = R6*S1 + R7*S4 + R8*S7;
    float RS8 = R6*S2 + R7*S5 + R8*S8;

    // Sc = RS * R^T
    float Sc0 = RS0*R0 + RS1*R1 + RS2*R2;
    float Sc1 = RS0*R3 + RS1*R4 + RS2*R5;
    float Sc2 = RS0*R6 + RS1*R7 + RS2*R8;
    float Sc3 = RS3*R0 + RS4*R1 + RS5*R2;
    float Sc4 = RS3*R3 + RS4*R4 + RS5*R5;
    float Sc5 = RS3*R6 + RS4*R7 + RS5*R8;
    float Sc6 = RS6*R0 + RS7*R1 + RS8*R2;
    float Sc7 = RS6*R3 + RS7*R4 + RS8*R5;
    float Sc8 = RS6*R6 + RS7*R7 + RS8*R8;

    // A = J * Sc (2x3)
    float A00 = J00*Sc0 + J02*Sc6;
    float A01 = J00*Sc1 + J02*Sc7;
    float A02 = J00*Sc2 + J02*Sc8;
    float A10 = J11*Sc3 + J12*Sc6;
    float A11 = J11*Sc4 + J12*Sc7;
    float A12 = J11*Sc5 + J12*Sc8;

    // cov2D = A * J^T + 1e-4 I
    float a = A00*J00 + A02*J02 + 1e-4f;
    float b = A01*J11 + A02*J12;
    float c = A10*J00 + A12*J02;
    float d = A11*J11 + A12*J12 + 1e-4f;

    float det = a*d - b*c;
    float invdet = 1.0f / det;
    float q0 = d*invdet;
    float q1 = -(b + c)*invdet;   // inv01+inv10, negative folded in
    float q2 = a*invdet;
    float c0 = opac[i] * 0.15915494309189535f / sqrtf(det);  // opacity/(2*pi*sqrt(det))
    if (!valid) { m2x = 0.f; m2y = 0.f; q0 = 0.f; q1 = 0.f; q2 = 0.f; c0 = 0.f; }

    float cr = colors[3*i+0], cg = colors[3*i+1], cb = colors[3*i+2];
    float* P = params + i*PSTRIDE;
    P[0] = m2x;  P[1] = m2y;  P[2] = q0;   P[3] = q1;
    P[4] = q2;   P[5] = c0;   P[6] = cr;   P[7] = cg;
    P[8] = cb;   P[9] = depth; P[10] = 0.f; P[11] = 0.f;
    depths[i] = depth;
}

// ---------------- stable rank sort (N^2 counting) + scatter ----------------
__global__ __launch_bounds__(256) void rank_kernel(
    const float* __restrict__ depths, const float* __restrict__ unsorted,
    float* __restrict__ sorted)
{
    __shared__ float sd[NGAUSS];
    int tid = threadIdx.x;
    for (int k = tid; k < NGAUSS; k += 256) sd[k] = depths[k];
    __syncthreads();
    int i = blockIdx.x * 256 + tid;
    if (i >= NGAUSS) return;
    float di = sd[i];
    int rank = 0;
    #pragma unroll 4
    for (int j = 0; j < NGAUSS; ++j) {
        float dj = sd[j];
        bool lt = (dj < di) || (dj == di && j < i);   // stable tie-break, matches jnp.argsort
        rank += lt ? 1 : 0;
    }
    const float4* src = (const float4*)(unsorted + (size_t)i*PSTRIDE);
    float4* dst = (float4*)(sorted + (size_t)rank*PSTRIDE);
    dst[0] = src[0]; dst[1] = src[1]; dst[2] = src[2];
}

// ---------------- render: per-pixel, per-depth-segment compositing ----------------
// Reference semantics: weight[0] = a_0;  weight[n>=1] = a_n * (1-a_n) * prod_{k<n}(1-a_k)
// (trans uses cum[1:], i.e. includes each gaussian's OWN (1-alpha) factor for n>=1).
__global__ __launch_bounds__(256) void render_kernel(
    const float* __restrict__ sorted, float4* __restrict__ segOut, int perSeg)
{
    __shared__ float sp[CHUNK*PSTRIDE];
    int tid = threadIdx.x;
    int seg = blockIdx.y;
    int p = blockIdx.x*256 + tid;
    float px = (float)(p & (IMW-1));
    float py = (float)(p >> 7);
    float Cr = 0.f, Cg = 0.f, Cb = 0.f, T = 1.f;
    int base = seg * perSeg;
    for (int off = 0; off < perSeg; off += CHUNK) {
        int cnt = min(CHUNK, perSeg - off);
        __syncthreads();
        const float* src = sorted + (size_t)(base + off)*PSTRIDE;
        for (int k = tid; k < cnt*PSTRIDE; k += 256) sp[k] = src[k];
        __syncthreads();
        int n0 = 0;
        if (base + off == 0) {
            // globally-first sorted gaussian: weight = alpha (no self (1-alpha) factor)
            const float* P = sp;
            float dx = px - P[0];
            float dy = py - P[1];
            float e = P[2]*dx*dx + P[3]*dx*dy + P[4]*dy*dy;
            float a1 = P[5] * __expf(-e);    // alpha
            float w = T * a1;                // T=1 here
            Cr = fmaf(w, P[6], Cr);
            Cg = fmaf(w, P[7], Cg);
            Cb = fmaf(w, P[8], Cb);
            T -= w;
            n0 = 1;
        }
        #pragma unroll 2
        for (int n = n0; n < cnt; ++n) {
            const float* P = sp + n*PSTRIDE;
            float dx = px - P[0];
            float dy = py - P[1];
            float e = P[2]*dx*dx + P[3]*dx*dy + P[4]*dy*dy;
            float g = __expf(-e);
            float a1 = P[5] * g;             // alpha
            float w = T * a1;                // T * alpha
            float f = fmaf(-a1, w, w);       // T * alpha * (1 - alpha)
            Cr = fmaf(f, P[6], Cr);
            Cg = fmaf(f, P[7], Cg);
            Cb = fmaf(f, P[8], Cb);
            T -= w;                          // T *= (1 - alpha)
        }
    }
    segOut[seg*NPIX + p] = make_float4(Cr, Cg, Cb, T);
}

// ---------------- combine segments in depth order ----------------
__global__ __launch_bounds__(256) void combine_kernel(
    const float4* __restrict__ segOut, float* __restrict__ out, int nSeg)
{
    int p = blockIdx.x*256 + threadIdx.x;
    float Cr = 0.f, Cg = 0.f, Cb = 0.f, T = 1.f;
    for (int s = 0; s < nSeg; ++s) {
        float4 v = segOut[s*NPIX + p];
        Cr = fmaf(T, v.x, Cr);
        Cg = fmaf(T, v.y, Cg);
        Cb = fmaf(T, v.z, Cb);
        T *= v.w;
    }
    out[3*p+0] = Cr; out[3*p+1] = Cg; out[3*p+2] = Cb;
}

extern "C" void kernel_launch(void* const* d_in, const int* in_sizes, int n_in,
                              void* d_out, int out_size, void* d_ws, size_t ws_size,
                              hipStream_t stream)
{
    const float* means3D = (const float*)d_in[0];
    const float* covs3d  = (const float*)d_in[1];
    const float* colors  = (const float*)d_in[2];
    const float* opac    = (const float*)d_in[3];
    const float* Km      = (const float*)d_in[4];
    const float* Rm      = (const float*)d_in[5];
    const float* tv      = (const float*)d_in[6];

    float* ws       = (float*)d_ws;
    float* unsorted = ws;              // NGAUSS*12 = 24000 floats
    float* depths   = ws + 24000;      // 2000 floats
    float* sorted   = ws + 26000;      // 24000 floats
    float* segOut   = ws + 50000;      // nSeg*NPIX*4 floats

    // choose segment count by available scratch
    int nSeg = 8;
    while (nSeg > 1 &&
           ws_size < ((size_t)50000 + (size_t)nSeg*NPIX*4) * sizeof(float))
        nSeg >>= 1;
    int perSeg = NGAUSS / nSeg;

    prep_kernel<<<(NGAUSS+255)/256, 256, 0, stream>>>(
        means3D, covs3d, colors, opac, Km, Rm, tv, unsorted, depths);
    rank_kernel<<<(NGAUSS+255)/256, 256, 0, stream>>>(depths, unsorted, sorted);
    dim3 rg(NPIX/256, nSeg);
    render_kernel<<<rg, 256, 0, stream>>>(sorted, (float4*)segOut, perSeg);
    combine_kernel<<<NPIX/256, 256, 0, stream>>>((float4*)segOut, (float*)d_out, nSeg);
}

// Round 3
// 40.047 us; speedup vs baseline: 2.1448x; 2.1448x over previous
//
#include <hip/hip_runtime.h>
#include <math.h>

#define NGAUSS 2000
#define IMW 128
#define IMH 128
#define NPIX (IMW*IMH)
#define PSTRIDE 12
#define MAXSEG 16
#define CHUNK 125   // NGAUSS/MAXSEG

// ---------------- preprocess: per-gaussian params ----------------
__global__ __launch_bounds__(256) void prep_kernel(
    const float* __restrict__ means3D, const float* __restrict__ covs3d,
    const float* __restrict__ colors, const float* __restrict__ opac,
    const float* __restrict__ Km, const float* __restrict__ Rm,
    const float* __restrict__ tv,
    float* __restrict__ params, float* __restrict__ depths)
{
    int i = blockIdx.x * 256 + threadIdx.x;
    if (i >= NGAUSS) return;

    float R0 = Rm[0], R1 = Rm[1], R2 = Rm[2];
    float R3 = Rm[3], R4 = Rm[4], R5 = Rm[5];
    float R6 = Rm[6], R7 = Rm[7], R8 = Rm[8];

    float mx = means3D[3*i+0], my = means3D[3*i+1], mz = means3D[3*i+2];
    float camx = R0*mx + R1*my + R2*mz + tv[0];
    float camy = R3*mx + R4*my + R5*mz + tv[1];
    float camz = R6*mx + R7*my + R8*mz + tv[2];

    float depth = fmaxf(camz, 1.0f);
    bool valid = (depth > 1.0f) && (depth < 50.0f);

    float fx = Km[0], cx = Km[2], fy = Km[4], cy = Km[5];
    float invz = 1.0f / camz;
    float m2x = (fx*camx + cx*camz) * invz;
    float m2y = (fy*camy + cy*camz) * invz;

    float J00 = fx*invz, J02 = -fx*camx*invz*invz;
    float J11 = fy*invz, J12 = -fy*camy*invz*invz;

    float S0 = covs3d[9*i+0], S1 = covs3d[9*i+1], S2 = covs3d[9*i+2];
    float S3 = covs3d[9*i+3], S4 = covs3d[9*i+4], S5 = covs3d[9*i+5];
    float S6 = covs3d[9*i+6], S7 = covs3d[9*i+7], S8 = covs3d[9*i+8];

    float RS0 = R0*S0 + R1*S3 + R2*S6;
    float RS1 = R0*S1 + R1*S4 + R2*S7;
    float RS2 = R0*S2 + R1*S5 + R2*S8;
    float RS3 = R3*S0 + R4*S3 + R5*S6;
    float RS4 = R3*S1 + R4*S4 + R5*S7;
    float RS5 = R3*S2 + R4*S5 + R5*S8;
    float RS6 = R6*S0 + R7*S3 + R8*S6;
    float RS7 = R6*S1 + R7*S4 + R8*S7;
    float RS8 = R6*S2 + R7*S5 + R8*S8;

    float Sc0 = RS0*R0 + RS1*R1 + RS2*R2;
    float Sc1 = RS0*R3 + RS1*R4 + RS2*R5;
    float Sc2 = RS0*R6 + RS1*R7 + RS2*R8;
    float Sc3 = RS3*R0 + RS4*R1 + RS5*R2;
    float Sc4 = RS3*R3 + RS4*R4 + RS5*R5;
    float Sc5 = RS3*R6 + RS4*R7 + RS5*R8;
    float Sc6 = RS6*R0 + RS7*R1 + RS8*R2;
    float Sc7 = RS6*R3 + RS7*R4 + RS8*R5;
    float Sc8 = RS6*R6 + RS7*R7 + RS8*R8;

    float A00 = J00*Sc0 + J02*Sc6;
    float A01 = J00*Sc1 + J02*Sc7;
    float A02 = J00*Sc2 + J02*Sc8;
    float A10 = J11*Sc3 + J12*Sc6;
    float A11 = J11*Sc4 + J12*Sc7;
    float A12 = J11*Sc5 + J12*Sc8;

    float a = A00*J00 + A02*J02 + 1e-4f;
    float b = A01*J11 + A02*J12;
    float c = A10*J00 + A12*J02;
    float d = A11*J11 + A12*J12 + 1e-4f;

    float det = a*d - b*c;
    float invdet = 1.0f / det;
    float q0 = d*invdet;
    float q1 = -(b + c)*invdet;
    float q2 = a*invdet;
    float c0 = opac[i] * 0.15915494309189535f / sqrtf(det);
    if (!valid) { m2x = 0.f; m2y = 0.f; q0 = 0.f; q1 = 0.f; q2 = 0.f; c0 = 0.f; }

    float cr = colors[3*i+0], cg = colors[3*i+1], cb = colors[3*i+2];
    float* P = params + i*PSTRIDE;
    P[0] = m2x;  P[1] = m2y;  P[2] = q0;   P[3] = q1;
    P[4] = q2;   P[5] = c0;   P[6] = cr;   P[7] = cg;
    P[8] = cb;   P[9] = depth; P[10] = 0.f; P[11] = 0.f;
    depths[i] = depth;
}

// ---------------- stable rank sort: one wave per gaussian ----------------
__global__ __launch_bounds__(64) void rank_kernel(
    const float* __restrict__ depths, const float* __restrict__ unsorted,
    float* __restrict__ sorted)
{
    int i = blockIdx.x;
    int lane = threadIdx.x;
    float di = depths[i];
    int rank = 0;
    for (int j = lane; j < NGAUSS; j += 64) {
        float dj = depths[j];
        rank += ((dj < di) || (dj == di && j < i)) ? 1 : 0;   // stable tie-break
    }
    #pragma unroll
    for (int o = 32; o > 0; o >>= 1) rank += __shfl_down(rank, o, 64);
    rank = __shfl(rank, 0, 64);
    if (lane < 3) {
        const float4* src = (const float4*)(unsorted + (size_t)i*PSTRIDE);
        float4* dst = (float4*)(sorted + (size_t)rank*PSTRIDE);
        dst[lane] = src[lane];
    }
}

// ---------------- render: per-pixel, per-depth-segment compositing ----------------
// Reference semantics: weight[0] = a_0;  weight[n>=1] = a_n * (1-a_n) * prod_{k<n}(1-a_k)
__global__ __launch_bounds__(256) void render_kernel(
    const float* __restrict__ sorted, float4* __restrict__ segOut, int perSeg)
{
    __shared__ float4 sp[CHUNK*3];
    int tid = threadIdx.x;
    int seg = blockIdx.y;
    int p = blockIdx.x*256 + tid;
    float px = (float)(p & (IMW-1));
    float py = (float)(p >> 7);
    float Cr = 0.f, Cg = 0.f, Cb = 0.f, T = 1.f;
    int base = seg * perSeg;
    for (int off = 0; off < perSeg; off += CHUNK) {
        int cnt = min(CHUNK, perSeg - off);
        __syncthreads();
        const float4* src = (const float4*)(sorted + (size_t)(base + off)*PSTRIDE);
        for (int k = tid; k < cnt*3; k += 256) sp[k] = src[k];
        __syncthreads();
        int n0 = 0;
        if (base + off == 0) {
            // globally-first sorted gaussian: weight = alpha (no self (1-alpha) factor)
            float4 v0 = sp[0], v1 = sp[1], v2 = sp[2];
            float dx = px - v0.x;
            float dy = py - v0.y;
            float e = v0.z*dx*dx + v0.w*dx*dy + v1.x*dy*dy;
            float a1 = v1.y * __expf(-e);
            float w = a1;                       // T = 1
            Cr = fmaf(w, v1.z, Cr);
            Cg = fmaf(w, v1.w, Cg);
            Cb = fmaf(w, v2.x, Cb);
            T -= w;
            n0 = 1;
        }
        for (int n = n0; n < cnt; ++n) {
            float4 v0 = sp[n*3+0], v1 = sp[n*3+1], v2 = sp[n*3+2];
            float dx = px - v0.x;
            float dy = py - v0.y;
            float e = v0.z*dx*dx + v0.w*dx*dy + v1.x*dy*dy;
            float g = __expf(-e);
            float a1 = v1.y * g;                // alpha
            float w = T * a1;                   // T * alpha
            float f = fmaf(-a1, w, w);          // T * alpha * (1 - alpha)
            Cr = fmaf(f, v1.z, Cr);
            Cg = fmaf(f, v1.w, Cg);
            Cb = fmaf(f, v2.x, Cb);
            T -= w;                             // T *= (1 - alpha)
        }
    }
    segOut[seg*NPIX + p] = make_float4(Cr, Cg, Cb, T);
}

// ---------------- combine segments in depth order ----------------
__global__ __launch_bounds__(256) void combine_kernel(
    const float4* __restrict__ segOut, float* __restrict__ out, int nSeg)
{
    int p = blockIdx.x*256 + threadIdx.x;
    float Cr = 0.f, Cg = 0.f, Cb = 0.f, T = 1.f;
    for (int s = 0; s < nSeg; ++s) {
        float4 v = segOut[s*NPIX + p];
        Cr = fmaf(T, v.x, Cr);
        Cg = fmaf(T, v.y, Cg);
        Cb = fmaf(T, v.z, Cb);
        T *= v.w;
    }
    out[3*p+0] = Cr; out[3*p+1] = Cg; out[3*p+2] = Cb;
}

extern "C" void kernel_launch(void* const* d_in, const int* in_sizes, int n_in,
                              void* d_out, int out_size, void* d_ws, size_t ws_size,
                              hipStream_t stream)
{
    const float* means3D = (const float*)d_in[0];
    const float* covs3d  = (const float*)d_in[1];
    const float* colors  = (const float*)d_in[2];
    const float* opac    = (const float*)d_in[3];
    const float* Km      = (const float*)d_in[4];
    const float* Rm      = (const float*)d_in[5];
    const float* tv      = (const float*)d_in[6];

    float* ws       = (float*)d_ws;
    float* unsorted = ws;              // NGAUSS*12 = 24000 floats
    float* depths   = ws + 24000;      // 2000 floats
    float* sorted   = ws + 26000;      // 24000 floats
    float* segOut   = ws + 50000;      // nSeg*NPIX*4 floats

    // choose segment count by available scratch
    int nSeg = MAXSEG;
    while (nSeg > 1 &&
           ws_size < ((size_t)50000 + (size_t)nSeg*NPIX*4) * sizeof(float))
        nSeg >>= 1;
    int perSeg = NGAUSS / nSeg;

    prep_kernel<<<(NGAUSS+255)/256, 256, 0, stream>>>(
        means3D, covs3d, colors, opac, Km, Rm, tv, unsorted, depths);
    rank_kernel<<<NGAUSS, 64, 0, stream>>>(depths, unsorted, sorted);
    dim3 rg(NPIX/256, nSeg);
    render_kernel<<<rg, 256, 0, stream>>>(sorted, (float4*)segOut, perSeg);
    combine_kernel<<<NPIX/256, 256, 0, stream>>>((float4*)segOut, (float*)d_out, nSeg);
}